// Round 4
// baseline (810.954 us; speedup 1.0000x reference)
//
#include <hip/hip_runtime.h>
#include <hip/hip_bf16.h>

// Social-LSTM on MI355X. fp32 I/O.
// te = relu( (sum_{(p,g) in nz(grid[n])} U[p,g,:]) + b_soc ),
// U = h @ W_soc_g (register-tiled VALU GEMM).
// Grid scanned ONCE into a per-(row,wave) u16 CSR (k_csr); per frame only
// k_U + k_fused (pool-gather + gates + LSTM + out-proj) run.

#define TT   12
#define NN   1000
#define RNNW 128
#define EMBW 64
#define GGW  16
#define OUTD 5
#define UCW  (GGW*EMBW)   // 1024
#define GROW (NN*GGW)     // 16000 floats per (t,n) grid row
#define RCAP 256          // per-wave CSR capacity (8 waves -> 2048/row)

__device__ __forceinline__ float sigmf(float x) { return 1.f / (1.f + __expf(-x)); }

// ---- prep: h/c init + weight transposes (once per launch) ---------------
// WsT[gk][e] = W_soc[e][gk]  (2048 x 64)
// WcT[k][j]  = k<128 ? W_ih[j][k] : W_hh[j][k-128]   (256 x 512)
__global__ void k_prep(const float* __restrict__ h0, const float* __restrict__ c0,
                       const float* __restrict__ W_soc,
                       const float* __restrict__ W_ih, const float* __restrict__ W_hh,
                       float* __restrict__ h, float* __restrict__ c,
                       float* __restrict__ WsT, float* __restrict__ WcT) {
    int i = blockIdx.x * 256 + threadIdx.x;
    if (i < 131072) {
        int e = i >> 11, gk = i & 2047;
        WsT[gk * 64 + e] = W_soc[i];
    } else if (i < 196608) {
        int i2 = i - 131072;              // W_ih [512][128]
        int j = i2 >> 7, k = i2 & 127;
        WcT[k * 512 + j] = W_ih[i2];
    } else if (i < 262144) {
        int i3 = i - 196608;              // W_hh
        int j = i3 >> 7, k = i3 & 127;
        WcT[(128 + k) * 512 + j] = W_hh[i3];
    } else if (i < 262144 + NN * RNNW) {
        int i4 = i - 262144; h[i4] = h0[i4];
    } else if (i < 262144 + 2 * NN * RNNW) {
        int i5 = i - 262144 - NN * RNNW; c[i5] = c0[i5];
    }
}

// ---- one-shot grid compaction: block per (t,n) row ----------------------
// wave w scans windows {it*8+w}, appends flat indices to its private region.
// Deterministic: fixed window->wave map, lane-ascending write order.
__global__ __launch_bounds__(512) void k_csr(const unsigned int* __restrict__ grids,
                                             unsigned short* __restrict__ idx,
                                             unsigned short* __restrict__ cnt) {
    const int row = blockIdx.x;                    // 0..TT*NN-1
    const int lane = threadIdx.x & 63, wave = threadIdx.x >> 6;
    const unsigned int* gp = grids + (size_t)row * GROW;
    unsigned short* wIdx = idx + (size_t)row * (8 * RCAP) + wave * RCAP;
    int wcnt = 0;
    for (int it = 0; it < 8; ++it) {
        int base = (it * 8 + wave) * 256;
        if (base >= GROW) break;
        int f0 = base + lane * 4;
        uint4 v = {0u, 0u, 0u, 0u};
        if (f0 < GROW) v = *(const uint4*)(gp + f0);   // GROW%4==0 -> safe
        unsigned int va[4] = {v.x, v.y, v.z, v.w};
        #pragma unroll
        for (int sub = 0; sub < 4; ++sub) {
            bool nz = (va[sub] != 0u);
            unsigned long long m = __ballot(nz);
            if (nz) {
                int r = __popcll(m & ((1ull << lane) - 1ull));
                int slot = wcnt + r;
                if (slot < RCAP) wIdx[slot] = (unsigned short)(f0 + sub);
            }
            wcnt += __popcll(m);
        }
    }
    if (lane == 0) cnt[row * 8 + wave] = (unsigned short)(wcnt > RCAP ? 0xFFFF : wcnt);
}

// ---- U[p, g*64+e] = sum_k h[p,k] * WsT[g*128+k][e] ---------------------
// grid (16,16): 16 p-tiles of 64, blockIdx.y = g. 256 thr, thread = 4x4.
__global__ __launch_bounds__(256) void k_U(const float* __restrict__ h,
                                           const float* __restrict__ WsT,
                                           float* __restrict__ U) {
    __shared__ float sAT[RNNW][64];
    __shared__ float sBT[RNNW][64];
    const int tid = threadIdx.x;
    const int p0 = blockIdx.x * 64;
    const int g  = blockIdx.y;
    {   // stage sAT: transpose h[p0+pp][k] -> sAT[k][pp]
        int pp = tid >> 2, kq = (tid & 3) * 4;
        int p = p0 + pp;
        #pragma unroll
        for (int pass = 0; pass < 8; ++pass) {
            int k0 = pass * 16 + kq;
            float4 v = {0.f, 0.f, 0.f, 0.f};
            if (p < NN) v = *(const float4*)(h + (size_t)p * RNNW + k0);
            sAT[k0 + 0][pp] = v.x; sAT[k0 + 1][pp] = v.y;
            sAT[k0 + 2][pp] = v.z; sAT[k0 + 3][pp] = v.w;
        }
    }
    {   // stage sBT
        #pragma unroll
        for (int pass = 0; pass < 8; ++pass) {
            int f = pass * 256 + tid;
            int k = f >> 4, e4 = (f & 15) * 4;
            float4 v = *(const float4*)(WsT + (size_t)(g * 128 + k) * 64 + e4);
            *(float4*)(&sBT[k][e4]) = v;
        }
    }
    __syncthreads();
    const int tx = tid & 15, ty = tid >> 4;
    float acc[4][4];
    #pragma unroll
    for (int i = 0; i < 4; i++)
        #pragma unroll
        for (int j = 0; j < 4; j++) acc[i][j] = 0.f;
    #pragma unroll 4
    for (int k = 0; k < RNNW; ++k) {
        float4 a4 = *(const float4*)(&sAT[k][ty * 4]);
        float4 b4 = *(const float4*)(&sBT[k][tx * 4]);
        const float av[4] = {a4.x, a4.y, a4.z, a4.w};
        const float bv[4] = {b4.x, b4.y, b4.z, b4.w};
        #pragma unroll
        for (int i = 0; i < 4; i++)
            #pragma unroll
            for (int j = 0; j < 4; j++) acc[i][j] += av[i] * bv[j];
    }
    #pragma unroll
    for (int i = 0; i < 4; i++) {
        int p = p0 + ty * 4 + i;
        if (p < NN) {
            float4 v = {acc[i][0], acc[i][1], acc[i][2], acc[i][3]};
            *(float4*)(U + (size_t)p * UCW + g * EMBW + tx * 4) = v;
        }
    }
}

// ---- fused pool + gates + LSTM + out-proj: block owns 4 pedestrians -----
__global__ __launch_bounds__(512) void k_fused(const unsigned int* __restrict__ grids,
                                               const unsigned short* __restrict__ idx,
                                               const unsigned short* __restrict__ cnt,
                                               const float* __restrict__ x_in,
                                               const float* __restrict__ U,
                                               const float* __restrict__ WcT,
                                               const float* __restrict__ W_in,
                                               const float* __restrict__ b_in,
                                               const float* __restrict__ b_soc,
                                               const float* __restrict__ b_ih,
                                               const float* __restrict__ b_hh,
                                               const float* __restrict__ W_out,
                                               const float* __restrict__ b_out,
                                               float* __restrict__ A,
                                               float* __restrict__ h,
                                               float* __restrict__ c,
                                               float* __restrict__ out, int t) {
    __shared__ float sAcc[8][64];
    __shared__ float sG[4][512];
    __shared__ float shv[4][128];
    const int tid = threadIdx.x;
    const int lane = tid & 63, wave = tid >> 6;
    const int n0 = blockIdx.x * 4;

    // ---- phase 1: social pooling gather (2 waves per pedestrian) --------
    {
        const int nl = wave >> 1, half = wave & 1;
        const int row = t * NN + (n0 + nl);
        float acc = 0.f;
        bool fallback = false;
        #pragma unroll
        for (int q = 0; q < 4; ++q)
            if (cnt[row * 8 + half * 4 + q] == 0xFFFF) fallback = true;
        if (!fallback) {
            #pragma unroll
            for (int q = 0; q < 4; ++q) {
                const int cw = cnt[row * 8 + half * 4 + q];
                const unsigned short* ip = idx + (size_t)row * (8 * RCAP) + (half * 4 + q) * RCAP;
                int i = 0;
                for (; i + 4 <= cw; i += 4) {
                    int f0 = ip[i], f1 = ip[i + 1], f2 = ip[i + 2], f3 = ip[i + 3];
                    float u0 = U[((f0 >> 4) << 10) + ((f0 & 15) << 6) + lane];
                    float u1 = U[((f1 >> 4) << 10) + ((f1 & 15) << 6) + lane];
                    float u2 = U[((f2 >> 4) << 10) + ((f2 & 15) << 6) + lane];
                    float u3 = U[((f3 >> 4) << 10) + ((f3 & 15) << 6) + lane];
                    acc += u0; acc += u1; acc += u2; acc += u3;
                }
                for (; i < cw; ++i) {
                    int f = ip[i];
                    acc += U[((f >> 4) << 10) + ((f & 15) << 6) + lane];
                }
            }
        } else {  // adversarial-density fallback: rescan raw grid windows
            const unsigned int* gp = grids + (size_t)row * GROW;
            #pragma unroll
            for (int q = 0; q < 4; ++q) {
                int wv = half * 4 + q;
                for (int it = 0; it < 8; ++it) {
                    int base = (it * 8 + wv) * 256;
                    if (base >= GROW) continue;
                    int f0 = base + lane * 4;
                    uint4 v = {0u, 0u, 0u, 0u};
                    if (f0 < GROW) v = *(const uint4*)(gp + f0);
                    unsigned int va[4] = {v.x, v.y, v.z, v.w};
                    #pragma unroll
                    for (int sub = 0; sub < 4; ++sub) {
                        unsigned long long m = __ballot(va[sub] != 0u);
                        while (m) {
                            int b = __builtin_ctzll(m); m &= m - 1;
                            int f = base + b * 4 + sub;
                            acc += U[((f >> 4) << 10) + ((f & 15) << 6) + lane];
                        }
                    }
                }
            }
        }
        sAcc[wave][lane] = acc;
    }
    __syncthreads();
    // ---- combine halves, apply relu/bias, input embedding -> A (global)
    if (tid < 256) {
        int nl = tid >> 6, e = tid & 63;
        int n = n0 + nl;
        float te = fmaxf(sAcc[2 * nl][e] + sAcc[2 * nl + 1][e] + b_soc[e], 0.f);
        float x0 = x_in[((size_t)t * NN + n) * 2 + 0];
        float x1 = x_in[((size_t)t * NN + n) * 2 + 1];
        float ie = fmaxf(W_in[e * 2 + 0] * x0 + W_in[e * 2 + 1] * x1 + b_in[e], 0.f);
        A[(size_t)n * 128 + e]      = ie;
        A[(size_t)n * 128 + 64 + e] = te;
    }
    __syncthreads();
    // ---- phase 2: gates. thread j computes gate j for all 4 pedestrians.
    // A/h reads are wave-uniform (SGPR path); W reads coalesced from L2.
    {
        const int j = tid;
        const float* An = A + (size_t)n0 * 128;
        const float* hn = h + (size_t)n0 * 128;
        float g0 = 0.f, g1 = 0.f, g2 = 0.f, g3 = 0.f;
        #pragma unroll 8
        for (int k = 0; k < 128; ++k) {
            float w = WcT[k * 512 + j];
            g0 += An[0 * 128 + k] * w; g1 += An[1 * 128 + k] * w;
            g2 += An[2 * 128 + k] * w; g3 += An[3 * 128 + k] * w;
        }
        #pragma unroll 8
        for (int k = 0; k < 128; ++k) {
            float w = WcT[(128 + k) * 512 + j];
            g0 += hn[0 * 128 + k] * w; g1 += hn[1 * 128 + k] * w;
            g2 += hn[2 * 128 + k] * w; g3 += hn[3 * 128 + k] * w;
        }
        float bias = b_ih[j] + b_hh[j];
        sG[0][j] = g0 + bias; sG[1][j] = g1 + bias;
        sG[2][j] = g2 + bias; sG[3][j] = g3 + bias;
    }
    __syncthreads();
    // ---- phase 3: LSTM elementwise ----
    {
        int nl = tid >> 7, r = tid & 127;
        int n = n0 + nl;
        float gi = sG[nl][r], gf = sG[nl][128 + r], gg = sG[nl][256 + r], go = sG[nl][384 + r];
        float cn = sigmf(gf) * c[(size_t)n * RNNW + r] + sigmf(gi) * tanhf(gg);
        float hn = sigmf(go) * tanhf(cn);
        c[(size_t)n * RNNW + r] = cn;
        h[(size_t)n * RNNW + r] = hn;
        shv[nl][r] = hn;
    }
    __syncthreads();
    // ---- out projection ----
    if ((tid & 127) < OUTD) {
        int nl = tid >> 7, r = tid & 127, n = n0 + nl;
        float s = b_out[r];
        const float* wr = W_out + r * RNNW;
        for (int k = 0; k < RNNW; ++k) s += shv[nl][k] * wr[k];
        out[((size_t)t * NN + n) * OUTD + r] = s;
    }
}

// ---- final: fp32 h,c -> tail of d_out ----------------------------------
__global__ void k_final(const float* __restrict__ h, const float* __restrict__ c,
                        float* __restrict__ out) {
    int i = blockIdx.x * 256 + threadIdx.x;
    if (i < NN * RNNW) {
        out[TT * NN * OUTD + i] = h[i];
        out[TT * NN * OUTD + NN * RNNW + i] = c[i];
    }
}

extern "C" void kernel_launch(void* const* d_in, const int* in_sizes, int n_in,
                              void* d_out, int out_size, void* d_ws, size_t ws_size,
                              hipStream_t stream) {
    const float* x_in        = (const float*)d_in[0];
    const unsigned int* grd  = (const unsigned int*)d_in[1];
    const float* h0          = (const float*)d_in[2];
    const float* c0          = (const float*)d_in[3];
    const float* W_in        = (const float*)d_in[4];
    const float* b_in        = (const float*)d_in[5];
    const float* W_soc       = (const float*)d_in[6];
    const float* b_soc       = (const float*)d_in[7];
    const float* W_ih        = (const float*)d_in[8];
    const float* W_hh        = (const float*)d_in[9];
    const float* b_ih        = (const float*)d_in[10];
    const float* b_hh        = (const float*)d_in[11];
    const float* W_out       = (const float*)d_in[12];
    const float* b_out       = (const float*)d_in[13];
    float* out = (float*)d_out;

    float* h     = (float*)d_ws;                  // 128000
    float* c     = h + NN * RNNW;                 // 128000
    float* U     = c + NN * RNNW;                 // 1,024,000
    float* A     = U + (size_t)NN * UCW;          // 128,000
    float* WsT   = A + (size_t)NN * 128;          // 131,072
    float* WcT   = WsT + 2048 * 64;               // 131,072
    unsigned short* cnt = (unsigned short*)(WcT + 256 * 512);   // TT*NN*8 u16
    unsigned short* idx = cnt + (size_t)TT * NN * 8;            // TT*NN*2048 u16 (~98 MB)

    hipLaunchKernelGGL(k_prep, dim3(2024), dim3(256), 0, stream,
                       h0, c0, W_soc, W_ih, W_hh, h, c, WsT, WcT);
    hipLaunchKernelGGL(k_csr, dim3(TT * NN), dim3(512), 0, stream, grd, idx, cnt);
    for (int t = 0; t < TT; ++t) {
        hipLaunchKernelGGL(k_U, dim3(16, 16), dim3(256), 0, stream, h, WsT, U);
        hipLaunchKernelGGL(k_fused, dim3(NN / 4), dim3(512), 0, stream,
                           grd, idx, cnt, x_in, U, WcT, W_in, b_in, b_soc,
                           b_ih, b_hh, W_out, b_out, A, h, c, out, t);
    }
    hipLaunchKernelGGL(k_final, dim3(500), dim3(256), 0, stream, h, c, out);
}